// Round 1
// baseline (2287.304 us; speedup 1.0000x reference)
//
#include <hip/hip_runtime.h>

#define N_NODES 100000
#define N_EDGES 1600000
#define N_GRAPHS 128
#define NHID 128
#define NLAYER 4
#define BN_EPS 1e-5f

#define SCAN_ITEMS 1024
#define SCAN_NB ((N_NODES + SCAN_ITEMS - 1) / SCAN_ITEMS)   // 98

__device__ __forceinline__ float4 ld4(const float* p){ return *(const float4*)p; }
__device__ __forceinline__ void st4(float* p, float4 v){ *(float4*)p = v; }

// ---------------- CSR build ----------------

__global__ void k_hist(const int* __restrict__ dst, int* __restrict__ counts){
    int e = blockIdx.x * 256 + threadIdx.x;
    if (e < N_EDGES) atomicAdd(&counts[dst[e]], 1);
}

__global__ void k_scan_partial(const int* __restrict__ counts, int* __restrict__ partial){
    __shared__ int s[256];
    int t = threadIdx.x;
    int base = blockIdx.x * SCAN_ITEMS + t * 4;
    int v = 0;
    #pragma unroll
    for (int k = 0; k < 4; k++) if (base + k < N_NODES) v += counts[base + k];
    s[t] = v;
    __syncthreads();
    for (int o = 128; o > 0; o >>= 1){
        if (t < o) s[t] += s[t + o];
        __syncthreads();
    }
    if (t == 0) partial[blockIdx.x] = s[0];
}

__global__ void k_scan_top(int* __restrict__ partial, int nb, int* __restrict__ row_ptr){
    __shared__ int s[128];
    int t = threadIdx.x;
    int v = (t < nb) ? partial[t] : 0;
    s[t] = v;
    __syncthreads();
    for (int d = 1; d < 128; d <<= 1){
        int add = (t >= d) ? s[t - d] : 0;
        __syncthreads();
        s[t] += add;
        __syncthreads();
    }
    if (t < nb) partial[t] = s[t] - v;           // exclusive
    if (t == 0) row_ptr[N_NODES] = N_EDGES;
}

__global__ void k_scan_final(const int* __restrict__ counts, const int* __restrict__ partial,
                             int* __restrict__ row_ptr){
    __shared__ int s[256];
    int t = threadIdx.x;
    int base = blockIdx.x * SCAN_ITEMS + t * 4;
    int v[4]; int tsum = 0;
    #pragma unroll
    for (int k = 0; k < 4; k++){ v[k] = (base + k < N_NODES) ? counts[base + k] : 0; tsum += v[k]; }
    s[t] = tsum;
    __syncthreads();
    for (int d = 1; d < 256; d <<= 1){
        int add = (t >= d) ? s[t - d] : 0;
        __syncthreads();
        s[t] += add;
        __syncthreads();
    }
    int off = partial[blockIdx.x] + s[t] - tsum;  // exclusive prefix for this thread
    #pragma unroll
    for (int k = 0; k < 4; k++){
        if (base + k < N_NODES) row_ptr[base + k] = off;
        off += v[k];
    }
}

__global__ void k_fill(const int* __restrict__ eidx, const int* __restrict__ eattr,
                       int* __restrict__ cursor, unsigned* __restrict__ pack){
    int e = blockIdx.x * 256 + threadIdx.x;
    if (e >= N_EDGES) return;
    int d = eidx[N_EDGES + e];
    int s = eidx[e];
    int a = eattr[e];
    int pos = atomicAdd(&cursor[d], 1);
    pack[pos] = (unsigned)s | ((unsigned)a << 17);   // src<2^17, attr<32
}

// ---------------- node embedding init ----------------

__global__ void k_initx(const int* __restrict__ x_idx, const float* __restrict__ node_emb,
                        float4* __restrict__ x4){
    int i = blockIdx.x * 256 + threadIdx.x;          // over N*32 float4s
    if (i >= N_NODES * 32) return;
    int n = i >> 5, c = i & 31;
    int id = x_idx[n];
    x4[i] = ((const float4*)node_emb)[id * 32 + c];
}

// ---------------- aggregation: h0[n] = x[n] + sum relu(x[src]+emb[attr]) ----------------

__global__ void k_agg(const float* __restrict__ x, const int* __restrict__ row_ptr,
                      const unsigned* __restrict__ pack, const float* __restrict__ emb_l,
                      float2* __restrict__ h0){
    int gid = blockIdx.x * 256 + threadIdx.x;
    int node = gid >> 6;
    if (node >= N_NODES) return;
    int lane = threadIdx.x & 63;                     // 2 channels per lane
    const float2* x2 = (const float2*)x;
    const float2* e2 = (const float2*)emb_l;
    float2 acc = x2[node * 64 + lane];
    int beg = row_ptr[node], end = row_ptr[node + 1];
    for (int i = beg; i < end; i++){
        unsigned p = pack[i];
        int s = (int)(p & 0x1FFFFu);
        int a = (int)(p >> 17);
        float2 xv = x2[s * 64 + lane];
        float2 ev = e2[a * 64 + lane];
        acc.x += fmaxf(xv.x + ev.x, 0.f);
        acc.y += fmaxf(xv.y + ev.y, 0.f);
    }
    h0[node * 64 + lane] = acc;
}

// ---------------- fused MLP: h2 = relu(h0 @ w1) @ w2 (in-place safe per 128-row block) ----

__global__ __launch_bounds__(256) void k_mlp(const float* __restrict__ h0,
                                             const float* __restrict__ w1,
                                             const float* __restrict__ w2,
                                             float* __restrict__ out){
    __shared__ float As[128][36];    // 18.0 KB  (row-major, +4 pad keeps float4 align, 2-way banks)
    __shared__ float Bs[32][128];    // 16.0 KB
    __shared__ float Ts[128][132];   // 66.0 KB  -> total 100 KB, 1 block/CU
    const int tid = threadIdx.x;
    const int rt = tid & 15;         // adjacent-row thread id -> conflict-free-ish column reads
    const int ct = tid >> 4;
    const int row0 = blockIdx.x * 128;

    float acc[8][8];
    #pragma unroll
    for (int i = 0; i < 8; i++)
        #pragma unroll
        for (int j = 0; j < 8; j++) acc[i][j] = 0.f;

    // ---- phase 1: T = relu(h0 @ w1) ----
    for (int kc = 0; kc < 4; kc++){
        __syncthreads();
        #pragma unroll
        for (int q = 0; q < 4; q++){
            int f = tid + 256 * q;                  // 0..1023 float4s of A chunk
            int r = f >> 3, kq = f & 7;
            int gr = row0 + r;
            float4 v = make_float4(0.f, 0.f, 0.f, 0.f);
            if (gr < N_NODES) v = ld4(h0 + gr * NHID + kc * 32 + kq * 4);
            st4(&As[r][kq * 4], v);
        }
        #pragma unroll
        for (int q = 0; q < 4; q++){
            int f = tid + 256 * q;                  // 0..1023 float4s of W chunk
            int r = f >> 5, c4 = f & 31;
            st4(&Bs[r][c4 * 4], ld4(w1 + (kc * 32 + r) * NHID + c4 * 4));
        }
        __syncthreads();
        #pragma unroll
        for (int g = 0; g < 8; g++){                // groups of 4 k
            float av[8][4];
            #pragma unroll
            for (int i = 0; i < 8; i++){
                float4 t = ld4(&As[rt + 16 * i][g * 4]);
                av[i][0] = t.x; av[i][1] = t.y; av[i][2] = t.z; av[i][3] = t.w;
            }
            #pragma unroll
            for (int q = 0; q < 4; q++){
                float4 b0 = ld4(&Bs[g * 4 + q][ct * 8]);
                float4 b1 = ld4(&Bs[g * 4 + q][ct * 8 + 4]);
                float bv[8] = {b0.x, b0.y, b0.z, b0.w, b1.x, b1.y, b1.z, b1.w};
                #pragma unroll
                for (int i = 0; i < 8; i++)
                    #pragma unroll
                    for (int j = 0; j < 8; j++)
                        acc[i][j] = fmaf(av[i][q], bv[j], acc[i][j]);
            }
        }
    }
    // relu -> Ts
    #pragma unroll
    for (int i = 0; i < 8; i++){
        st4(&Ts[rt + 16 * i][ct * 8],
            make_float4(fmaxf(acc[i][0], 0.f), fmaxf(acc[i][1], 0.f),
                        fmaxf(acc[i][2], 0.f), fmaxf(acc[i][3], 0.f)));
        st4(&Ts[rt + 16 * i][ct * 8 + 4],
            make_float4(fmaxf(acc[i][4], 0.f), fmaxf(acc[i][5], 0.f),
                        fmaxf(acc[i][6], 0.f), fmaxf(acc[i][7], 0.f)));
        #pragma unroll
        for (int j = 0; j < 8; j++) acc[i][j] = 0.f;
    }

    // ---- phase 2: out = T @ w2 ----
    for (int kc = 0; kc < 4; kc++){
        __syncthreads();                            // Bs reads (phase1/prev) + Ts writes done
        #pragma unroll
        for (int q = 0; q < 4; q++){
            int f = tid + 256 * q;
            int r = f >> 5, c4 = f & 31;
            st4(&Bs[r][c4 * 4], ld4(w2 + (kc * 32 + r) * NHID + c4 * 4));
        }
        __syncthreads();
        #pragma unroll
        for (int g = 0; g < 8; g++){
            float av[8][4];
            #pragma unroll
            for (int i = 0; i < 8; i++){
                float4 t = ld4(&Ts[rt + 16 * i][kc * 32 + g * 4]);
                av[i][0] = t.x; av[i][1] = t.y; av[i][2] = t.z; av[i][3] = t.w;
            }
            #pragma unroll
            for (int q = 0; q < 4; q++){
                float4 b0 = ld4(&Bs[g * 4 + q][ct * 8]);
                float4 b1 = ld4(&Bs[g * 4 + q][ct * 8 + 4]);
                float bv[8] = {b0.x, b0.y, b0.z, b0.w, b1.x, b1.y, b1.z, b1.w};
                #pragma unroll
                for (int i = 0; i < 8; i++)
                    #pragma unroll
                    for (int j = 0; j < 8; j++)
                        acc[i][j] = fmaf(av[i][q], bv[j], acc[i][j]);
            }
        }
    }
    // store h2
    #pragma unroll
    for (int i = 0; i < 8; i++){
        int gr = row0 + rt + 16 * i;
        if (gr < N_NODES){
            st4(out + gr * NHID + ct * 8,
                make_float4(acc[i][0], acc[i][1], acc[i][2], acc[i][3]));
            st4(out + gr * NHID + ct * 8 + 4,
                make_float4(acc[i][4], acc[i][5], acc[i][6], acc[i][7]));
        }
    }
}

// ---------------- BN stats (sum, sumsq per channel) ----------------

__global__ void k_stats(const float4* __restrict__ h2, float* __restrict__ stats_l){
    __shared__ float s4[256][4];
    __shared__ float q4[256][4];
    int tid = threadIdx.x;
    int idx = blockIdx.x * 256 + tid;
    int stride = gridDim.x * 256;                 // multiple of 32 -> channel-consistent
    float s0=0,s1=0,s2=0,s3=0,q0=0,q1=0,q2=0,q3=0;
    for (int i = idx; i < N_NODES * 32; i += stride){
        float4 v = h2[i];
        s0 += v.x; q0 += v.x * v.x;
        s1 += v.y; q1 += v.y * v.y;
        s2 += v.z; q2 += v.z * v.z;
        s3 += v.w; q3 += v.w * v.w;
    }
    s4[tid][0]=s0; s4[tid][1]=s1; s4[tid][2]=s2; s4[tid][3]=s3;
    q4[tid][0]=q0; q4[tid][1]=q1; q4[tid][2]=q2; q4[tid][3]=q3;
    __syncthreads();
    if (tid < 32){
        #pragma unroll
        for (int k = 1; k < 8; k++){
            s0 += s4[tid + 32*k][0]; s1 += s4[tid + 32*k][1];
            s2 += s4[tid + 32*k][2]; s3 += s4[tid + 32*k][3];
            q0 += q4[tid + 32*k][0]; q1 += q4[tid + 32*k][1];
            q2 += q4[tid + 32*k][2]; q3 += q4[tid + 32*k][3];
        }
        atomicAdd(&stats_l[tid*4+0], s0); atomicAdd(&stats_l[tid*4+1], s1);
        atomicAdd(&stats_l[tid*4+2], s2); atomicAdd(&stats_l[tid*4+3], s3);
        atomicAdd(&stats_l[128+tid*4+0], q0); atomicAdd(&stats_l[128+tid*4+1], q1);
        atomicAdd(&stats_l[128+tid*4+2], q2); atomicAdd(&stats_l[128+tid*4+3], q3);
    }
}

__global__ void k_coef(const float* __restrict__ stats_l, const float* __restrict__ gamma,
                       const float* __restrict__ beta, float* __restrict__ coef_l){
    int c = threadIdx.x;                            // 128
    float mu  = stats_l[c] * (1.f / N_NODES);
    float var = stats_l[128 + c] * (1.f / N_NODES) - mu * mu;
    float a = gamma[c] * rsqrtf(var + BN_EPS);
    coef_l[c] = a;
    coef_l[128 + c] = beta[c] - mu * a;
}

// ---------------- normalize + relu + residual (x updated in place) ----------------

__global__ void k_norm(const float4* __restrict__ h2, float4* __restrict__ x,
                       const float* __restrict__ coef_l){
    int i = blockIdx.x * 256 + threadIdx.x;
    if (i >= N_NODES * 32) return;
    int g = (i & 31) * 4;
    float4 h = h2[i];
    float4 xv = x[i];
    float4 r;
    r.x = fmaxf(fmaf(h.x, coef_l[g+0], coef_l[128+g+0]), 0.f) + xv.x;
    r.y = fmaxf(fmaf(h.y, coef_l[g+1], coef_l[128+g+1]), 0.f) + xv.y;
    r.z = fmaxf(fmaf(h.z, coef_l[g+2], coef_l[128+g+2]), 0.f) + xv.z;
    r.w = fmaxf(fmaf(h.w, coef_l[g+3], coef_l[128+g+3]), 0.f) + xv.w;
    x[i] = r;
}

// ---------------- pooling: one block per graph (batch is sorted) ----------------

__global__ void k_pool(const float* __restrict__ x, const int* __restrict__ batch,
                       float* __restrict__ gbuf){
    int g = blockIdx.x;
    int lo = 0, hi = N_NODES;
    while (lo < hi){ int mid = (lo + hi) >> 1; if (batch[mid] < g) lo = mid + 1; else hi = mid; }
    int start = lo;
    hi = N_NODES;
    while (lo < hi){ int mid = (lo + hi) >> 1; if (batch[mid] < g + 1) lo = mid + 1; else hi = mid; }
    int end = lo;
    int c = threadIdx.x & 127;
    int half = threadIdx.x >> 7;
    float acc = 0.f;
    for (int n = start + half; n < end; n += 2) acc += x[n * NHID + c];
    __shared__ float s[256];
    s[threadIdx.x] = acc;
    __syncthreads();
    if (threadIdx.x < 128) gbuf[g * NHID + threadIdx.x] = s[threadIdx.x] + s[threadIdx.x + 128];
}

// ---------------- output head: Linear -> BN -> ReLU -> Linear ----------------

__global__ __launch_bounds__(512) void k_head(const float* __restrict__ gbuf,
                                              const float* __restrict__ w1,
                                              const float* __restrict__ b1,
                                              const float* __restrict__ gamma,
                                              const float* __restrict__ beta,
                                              const float* __restrict__ w2,
                                              const float* __restrict__ b2,
                                              float* __restrict__ out){
    __shared__ float o1[128][130];
    __shared__ float smu[128], srs[128];
    int t = threadIdx.x;
    int i = t >> 2;             // row 0..127
    int jq = t & 3;             // 32-col quarter
    float acc[32];
    #pragma unroll
    for (int j = 0; j < 32; j++) acc[j] = 0.f;
    for (int k = 0; k < 128; k++){
        float a = gbuf[i * NHID + k];
        const float* wr = w1 + k * NHID + jq * 32;
        #pragma unroll
        for (int j = 0; j < 32; j++) acc[j] = fmaf(a, wr[j], acc[j]);
    }
    #pragma unroll
    for (int j = 0; j < 32; j++) o1[i][jq * 32 + j] = acc[j] + b1[jq * 32 + j];
    __syncthreads();
    if (t < 128){
        float s = 0.f, q = 0.f;
        for (int r = 0; r < 128; r++){ float v = o1[r][t]; s += v; q += v * v; }
        float mu = s * (1.f / 128.f);
        float var = q * (1.f / 128.f) - mu * mu;
        smu[t] = mu;
        srs[t] = rsqrtf(var + BN_EPS);
    }
    __syncthreads();
    if (t < 128){
        float a2 = 0.f;
        for (int j = 0; j < 128; j++){
            float v = (o1[t][j] - smu[j]) * srs[j] * gamma[j] + beta[j];
            a2 += fmaxf(v, 0.f) * w2[j];
        }
        out[t] = a2 + b2[0];
    }
}

// ---------------- launch ----------------

extern "C" void kernel_launch(void* const* d_in, const int* in_sizes, int n_in,
                              void* d_out, int out_size, void* d_ws, size_t ws_size,
                              hipStream_t stream){
    const int*   x_idx    = (const int*)d_in[0];
    const int*   eidx     = (const int*)d_in[1];
    const int*   eattr    = (const int*)d_in[2];
    const int*   batch    = (const int*)d_in[3];
    const float* node_emb = (const float*)d_in[4];
    const float* edge_emb = (const float*)d_in[5];
    const float* conv_w1  = (const float*)d_in[6];
    const float* conv_w2  = (const float*)d_in[7];
    const float* bn_gamma = (const float*)d_in[8];
    const float* bn_beta  = (const float*)d_in[9];
    const float* out_w1   = (const float*)d_in[10];
    const float* out_b1   = (const float*)d_in[11];
    const float* out_bng  = (const float*)d_in[12];
    const float* out_bnb  = (const float*)d_in[13];
    const float* out_w2   = (const float*)d_in[14];
    const float* out_b2   = (const float*)d_in[15];
    float* out = (float*)d_out;

    char* base = (char*)d_ws;
    size_t off = 0;
    auto alloc = [&](size_t bytes) -> char* {
        char* r = base + off;
        off = (off + bytes + 255) & ~(size_t)255;
        return r;
    };
    float*    xbuf    = (float*)alloc((size_t)N_NODES * NHID * 4);   // 51.2 MB
    float*    h0buf   = (float*)alloc((size_t)N_NODES * NHID * 4);   // 51.2 MB (h0, then h2 in place)
    int*      row_ptr = (int*)alloc((size_t)(N_NODES + 1) * 4);
    int*      cursor  = (int*)alloc((size_t)N_NODES * 4);
    int*      counts  = (int*)alloc((size_t)N_NODES * 4);
    int*      partial = (int*)alloc(512 * 4);
    unsigned* pack    = (unsigned*)alloc((size_t)N_EDGES * 4);       // 6.4 MB
    float*    stats   = (float*)alloc(NLAYER * 256 * 4);
    float*    coef    = (float*)alloc(NLAYER * 256 * 4);
    float*    gbuf    = (float*)alloc((size_t)N_GRAPHS * NHID * 4);
    (void)ws_size; (void)in_sizes; (void)n_in; (void)out_size;

    hipMemsetAsync(counts, 0, (size_t)N_NODES * 4, stream);
    hipMemsetAsync(stats, 0, NLAYER * 256 * 4, stream);

    // CSR build (edges grouped by dst), once per call, reused across 4 layers
    k_hist<<<N_EDGES / 256, 256, 0, stream>>>(eidx + N_EDGES, counts);
    k_scan_partial<<<SCAN_NB, 256, 0, stream>>>(counts, partial);
    k_scan_top<<<1, 128, 0, stream>>>(partial, SCAN_NB, row_ptr);
    k_scan_final<<<SCAN_NB, 256, 0, stream>>>(counts, partial, row_ptr);
    hipMemcpyAsync(cursor, row_ptr, (size_t)N_NODES * 4, hipMemcpyDeviceToDevice, stream);
    k_fill<<<N_EDGES / 256, 256, 0, stream>>>(eidx, eattr, cursor, pack);

    k_initx<<<(N_NODES * 32) / 256, 256, 0, stream>>>(x_idx, node_emb, (float4*)xbuf);

    for (int l = 0; l < NLAYER; l++){
        k_agg<<<(N_NODES * 64) / 256, 256, 0, stream>>>(
            xbuf, row_ptr, pack, edge_emb + (size_t)l * 20 * NHID, (float2*)h0buf);
        k_mlp<<<(N_NODES + 127) / 128, 256, 0, stream>>>(
            h0buf, conv_w1 + (size_t)l * NHID * NHID, conv_w2 + (size_t)l * NHID * NHID, h0buf);
        k_stats<<<512, 256, 0, stream>>>((const float4*)h0buf, stats + l * 256);
        k_coef<<<1, 128, 0, stream>>>(stats + l * 256, bn_gamma + l * NHID, bn_beta + l * NHID,
                                      coef + l * 256);
        k_norm<<<(N_NODES * 32) / 256, 256, 0, stream>>>(
            (const float4*)h0buf, (float4*)xbuf, coef + l * 256);
    }

    k_pool<<<N_GRAPHS, 256, 0, stream>>>(xbuf, batch, gbuf);
    k_head<<<1, 512, 0, stream>>>(gbuf, out_w1, out_b1, out_bng, out_bnb, out_w2, out_b2, out);
}

// Round 2
// 1717.097 us; speedup vs baseline: 1.3321x; 1.3321x over previous
//
#include <hip/hip_runtime.h>

#define N_NODES 100000
#define N_EDGES 1600000
#define N_GRAPHS 128
#define NHID 128
#define NLAYER 4
#define BN_EPS 1e-5f

#define SCAN_ITEMS 1024
#define SCAN_NB ((N_NODES + SCAN_ITEMS - 1) / SCAN_ITEMS)   // 98

__device__ __forceinline__ float4 ld4(const float* p){ return *(const float4*)p; }
__device__ __forceinline__ void st4(float* p, float4 v){ *(float4*)p = v; }

// ---------------- CSR build ----------------

__global__ void k_hist(const int* __restrict__ dst, int* __restrict__ counts){
    int e = blockIdx.x * 256 + threadIdx.x;
    if (e < N_EDGES) atomicAdd(&counts[dst[e]], 1);
}

__global__ void k_scan_partial(const int* __restrict__ counts, int* __restrict__ partial){
    __shared__ int s[256];
    int t = threadIdx.x;
    int base = blockIdx.x * SCAN_ITEMS + t * 4;
    int v = 0;
    #pragma unroll
    for (int k = 0; k < 4; k++) if (base + k < N_NODES) v += counts[base + k];
    s[t] = v;
    __syncthreads();
    for (int o = 128; o > 0; o >>= 1){
        if (t < o) s[t] += s[t + o];
        __syncthreads();
    }
    if (t == 0) partial[blockIdx.x] = s[0];
}

__global__ void k_scan_top(int* __restrict__ partial, int nb, int* __restrict__ row_ptr){
    __shared__ int s[128];
    int t = threadIdx.x;
    int v = (t < nb) ? partial[t] : 0;
    s[t] = v;
    __syncthreads();
    for (int d = 1; d < 128; d <<= 1){
        int add = (t >= d) ? s[t - d] : 0;
        __syncthreads();
        s[t] += add;
        __syncthreads();
    }
    if (t < nb) partial[t] = s[t] - v;           // exclusive
    if (t == 0) row_ptr[N_NODES] = N_EDGES;
}

__global__ void k_scan_final(const int* __restrict__ counts, const int* __restrict__ partial,
                             int* __restrict__ row_ptr){
    __shared__ int s[256];
    int t = threadIdx.x;
    int base = blockIdx.x * SCAN_ITEMS + t * 4;
    int v[4]; int tsum = 0;
    #pragma unroll
    for (int k = 0; k < 4; k++){ v[k] = (base + k < N_NODES) ? counts[base + k] : 0; tsum += v[k]; }
    s[t] = tsum;
    __syncthreads();
    for (int d = 1; d < 256; d <<= 1){
        int add = (t >= d) ? s[t - d] : 0;
        __syncthreads();
        s[t] += add;
        __syncthreads();
    }
    int off = partial[blockIdx.x] + s[t] - tsum;  // exclusive prefix for this thread
    #pragma unroll
    for (int k = 0; k < 4; k++){
        if (base + k < N_NODES) row_ptr[base + k] = off;
        off += v[k];
    }
}

__global__ void k_fill(const int* __restrict__ eidx, const int* __restrict__ eattr,
                       int* __restrict__ cursor, unsigned* __restrict__ pack){
    int e = blockIdx.x * 256 + threadIdx.x;
    if (e >= N_EDGES) return;
    int d = eidx[N_EDGES + e];
    int s = eidx[e];
    int a = eattr[e];
    int pos = atomicAdd(&cursor[d], 1);
    pack[pos] = (unsigned)s | ((unsigned)a << 17);   // src<2^17, attr<32
}

// ---------------- node embedding init ----------------

__global__ void k_initx(const int* __restrict__ x_idx, const float* __restrict__ node_emb,
                        float4* __restrict__ x4){
    int i = blockIdx.x * 256 + threadIdx.x;          // over N*32 float4s
    if (i >= N_NODES * 32) return;
    int n = i >> 5, c = i & 31;
    int id = x_idx[n];
    x4[i] = ((const float4*)node_emb)[id * 32 + c];
}

// ---------------- aggregation: h0[n] = x[n] + sum relu(x[src]+emb[attr]) ----------------

__global__ __launch_bounds__(256) void k_agg(const float* __restrict__ x,
                      const int* __restrict__ row_ptr,
                      const unsigned* __restrict__ pack, const float* __restrict__ emb_l,
                      float2* __restrict__ h0){
    __shared__ float2 s_emb[20 * 64];                // 10 KB: whole edge-emb table for this layer
    for (int i = threadIdx.x; i < 20 * 64; i += 256)
        s_emb[i] = ((const float2*)emb_l)[i];
    __syncthreads();

    int gid = blockIdx.x * 256 + threadIdx.x;        // grid exactly N_NODES*64/256
    int node = gid >> 6;
    int lane = threadIdx.x & 63;                     // 2 channels per lane
    const float2* x2 = (const float2*)x;
    float2 acc = x2[node * 64 + lane];
    int beg = row_ptr[node], end = row_ptr[node + 1];
    int i = beg;
    for (; i + 1 < end; i += 2){
        unsigned p0 = pack[i], p1 = pack[i + 1];
        float2 xv0 = x2[(p0 & 0x1FFFFu) * 64 + lane];
        float2 xv1 = x2[(p1 & 0x1FFFFu) * 64 + lane];
        float2 ev0 = s_emb[(p0 >> 17) * 64 + lane];
        float2 ev1 = s_emb[(p1 >> 17) * 64 + lane];
        acc.x += fmaxf(xv0.x + ev0.x, 0.f) + fmaxf(xv1.x + ev1.x, 0.f);
        acc.y += fmaxf(xv0.y + ev0.y, 0.f) + fmaxf(xv1.y + ev1.y, 0.f);
    }
    if (i < end){
        unsigned p = pack[i];
        float2 xv = x2[(p & 0x1FFFFu) * 64 + lane];
        float2 ev = s_emb[(p >> 17) * 64 + lane];
        acc.x += fmaxf(xv.x + ev.x, 0.f);
        acc.y += fmaxf(xv.y + ev.y, 0.f);
    }
    h0[node * 64 + lane] = acc;
}

// ---- fused MLP: h2 = relu(h0 @ w1) @ w2, + fused BN partial stats (atomicAdd) ----

__global__ __launch_bounds__(256) void k_mlp(const float* __restrict__ h0,
                                             const float* __restrict__ w1,
                                             const float* __restrict__ w2,
                                             float* __restrict__ out,
                                             float* __restrict__ stats_l){
    __shared__ float As[128][36];    // 18.0 KB
    __shared__ float Bs[32][128];    // 16.0 KB (also reused as stats scratch)
    __shared__ float Ts[128][132];   // 66.0 KB  -> total 100 KB, 1 block/CU
    const int tid = threadIdx.x;
    const int rt = tid & 15;
    const int ct = tid >> 4;
    const int row0 = blockIdx.x * 128;

    float acc[8][8];
    #pragma unroll
    for (int i = 0; i < 8; i++)
        #pragma unroll
        for (int j = 0; j < 8; j++) acc[i][j] = 0.f;

    // ---- phase 1: T = relu(h0 @ w1) ----
    for (int kc = 0; kc < 4; kc++){
        __syncthreads();
        #pragma unroll
        for (int q = 0; q < 4; q++){
            int f = tid + 256 * q;                  // 0..1023 float4s of A chunk
            int r = f >> 3, kq = f & 7;
            int gr = row0 + r;
            float4 v = make_float4(0.f, 0.f, 0.f, 0.f);
            if (gr < N_NODES) v = ld4(h0 + gr * NHID + kc * 32 + kq * 4);
            st4(&As[r][kq * 4], v);
        }
        #pragma unroll
        for (int q = 0; q < 4; q++){
            int f = tid + 256 * q;                  // 0..1023 float4s of W chunk
            int r = f >> 5, c4 = f & 31;
            st4(&Bs[r][c4 * 4], ld4(w1 + (kc * 32 + r) * NHID + c4 * 4));
        }
        __syncthreads();
        #pragma unroll
        for (int g = 0; g < 8; g++){                // groups of 4 k
            float av[8][4];
            #pragma unroll
            for (int i = 0; i < 8; i++){
                float4 t = ld4(&As[rt + 16 * i][g * 4]);
                av[i][0] = t.x; av[i][1] = t.y; av[i][2] = t.z; av[i][3] = t.w;
            }
            #pragma unroll
            for (int q = 0; q < 4; q++){
                float4 b0 = ld4(&Bs[g * 4 + q][ct * 8]);
                float4 b1 = ld4(&Bs[g * 4 + q][ct * 8 + 4]);
                float bv[8] = {b0.x, b0.y, b0.z, b0.w, b1.x, b1.y, b1.z, b1.w};
                #pragma unroll
                for (int i = 0; i < 8; i++)
                    #pragma unroll
                    for (int j = 0; j < 8; j++)
                        acc[i][j] = fmaf(av[i][q], bv[j], acc[i][j]);
            }
        }
    }
    // relu -> Ts
    #pragma unroll
    for (int i = 0; i < 8; i++){
        st4(&Ts[rt + 16 * i][ct * 8],
            make_float4(fmaxf(acc[i][0], 0.f), fmaxf(acc[i][1], 0.f),
                        fmaxf(acc[i][2], 0.f), fmaxf(acc[i][3], 0.f)));
        st4(&Ts[rt + 16 * i][ct * 8 + 4],
            make_float4(fmaxf(acc[i][4], 0.f), fmaxf(acc[i][5], 0.f),
                        fmaxf(acc[i][6], 0.f), fmaxf(acc[i][7], 0.f)));
        #pragma unroll
        for (int j = 0; j < 8; j++) acc[i][j] = 0.f;
    }

    // ---- phase 2: out = T @ w2 ----
    for (int kc = 0; kc < 4; kc++){
        __syncthreads();
        #pragma unroll
        for (int q = 0; q < 4; q++){
            int f = tid + 256 * q;
            int r = f >> 5, c4 = f & 31;
            st4(&Bs[r][c4 * 4], ld4(w2 + (kc * 32 + r) * NHID + c4 * 4));
        }
        __syncthreads();
        #pragma unroll
        for (int g = 0; g < 8; g++){
            float av[8][4];
            #pragma unroll
            for (int i = 0; i < 8; i++){
                float4 t = ld4(&Ts[rt + 16 * i][kc * 32 + g * 4]);
                av[i][0] = t.x; av[i][1] = t.y; av[i][2] = t.z; av[i][3] = t.w;
            }
            #pragma unroll
            for (int q = 0; q < 4; q++){
                float4 b0 = ld4(&Bs[g * 4 + q][ct * 8]);
                float4 b1 = ld4(&Bs[g * 4 + q][ct * 8 + 4]);
                float bv[8] = {b0.x, b0.y, b0.z, b0.w, b1.x, b1.y, b1.z, b1.w};
                #pragma unroll
                for (int i = 0; i < 8; i++)
                    #pragma unroll
                    for (int j = 0; j < 8; j++)
                        acc[i][j] = fmaf(av[i][q], bv[j], acc[i][j]);
            }
        }
    }
    // store h2
    #pragma unroll
    for (int i = 0; i < 8; i++){
        int gr = row0 + rt + 16 * i;
        if (gr < N_NODES){
            st4(out + gr * NHID + ct * 8,
                make_float4(acc[i][0], acc[i][1], acc[i][2], acc[i][3]));
            st4(out + gr * NHID + ct * 8 + 4,
                make_float4(acc[i][4], acc[i][5], acc[i][6], acc[i][7]));
        }
    }

    // ---- fused BN stats: padded rows are exactly 0 -> contribute nothing ----
    __syncthreads();                     // all Bs/Ts reads complete
    float* red = &Bs[0][0];              // 4096 floats: [16][128] sums + [16][128] sumsq
    #pragma unroll
    for (int j = 0; j < 8; j++){
        float s = 0.f, q = 0.f;
        #pragma unroll
        for (int i = 0; i < 8; i++){ float v = acc[i][j]; s += v; q += v * v; }
        red[rt * 128 + ct * 8 + j] = s;
        red[2048 + rt * 128 + ct * 8 + j] = q;
    }
    __syncthreads();
    if (tid < 128){
        float s = 0.f, q = 0.f;
        #pragma unroll
        for (int r2 = 0; r2 < 16; r2++){
            s += red[r2 * 128 + tid];
            q += red[2048 + r2 * 128 + tid];
        }
        atomicAdd(&stats_l[tid], s);
        atomicAdd(&stats_l[128 + tid], q);
    }
}

__global__ void k_coef(const float* __restrict__ stats_l, const float* __restrict__ gamma,
                       const float* __restrict__ beta, float* __restrict__ coef_l){
    int c = threadIdx.x;                            // 128
    float mu  = stats_l[c] * (1.f / N_NODES);
    float var = stats_l[128 + c] * (1.f / N_NODES) - mu * mu;
    float a = gamma[c] * rsqrtf(var + BN_EPS);
    coef_l[c] = a;
    coef_l[128 + c] = beta[c] - mu * a;
}

// ---------------- normalize + relu + residual (x updated in place) ----------------

__global__ void k_norm(const float4* __restrict__ h2, float4* __restrict__ x,
                       const float* __restrict__ coef_l){
    int i = blockIdx.x * 256 + threadIdx.x;
    if (i >= N_NODES * 32) return;
    int g = (i & 31) * 4;
    float4 h = h2[i];
    float4 xv = x[i];
    float4 r;
    r.x = fmaxf(fmaf(h.x, coef_l[g+0], coef_l[128+g+0]), 0.f) + xv.x;
    r.y = fmaxf(fmaf(h.y, coef_l[g+1], coef_l[128+g+1]), 0.f) + xv.y;
    r.z = fmaxf(fmaf(h.z, coef_l[g+2], coef_l[128+g+2]), 0.f) + xv.z;
    r.w = fmaxf(fmaf(h.w, coef_l[g+3], coef_l[128+g+3]), 0.f) + xv.w;
    x[i] = r;
}

// ---------------- pooling: one block per graph (batch is sorted) ----------------

__global__ void k_pool(const float* __restrict__ x, const int* __restrict__ batch,
                       float* __restrict__ gbuf){
    int g = blockIdx.x;
    int lo = 0, hi = N_NODES;
    while (lo < hi){ int mid = (lo + hi) >> 1; if (batch[mid] < g) lo = mid + 1; else hi = mid; }
    int start = lo;
    hi = N_NODES;
    while (lo < hi){ int mid = (lo + hi) >> 1; if (batch[mid] < g + 1) lo = mid + 1; else hi = mid; }
    int end = lo;
    int c = threadIdx.x & 127;
    int half = threadIdx.x >> 7;
    float acc = 0.f;
    for (int n = start + half; n < end; n += 2) acc += x[n * NHID + c];
    __shared__ float s[256];
    s[threadIdx.x] = acc;
    __syncthreads();
    if (threadIdx.x < 128) gbuf[g * NHID + threadIdx.x] = s[threadIdx.x] + s[threadIdx.x + 128];
}

// ---------------- output head: o1 = g @ w1 + b1 (parallel), then BN+ReLU+Linear ----

__global__ __launch_bounds__(128) void k_head1(const float* __restrict__ gbuf,
                                               const float* __restrict__ w1,
                                               const float* __restrict__ b1,
                                               float* __restrict__ o1){
    __shared__ float gs[128];
    int i = blockIdx.x;                  // graph row
    int j = threadIdx.x;                 // output column
    gs[j] = gbuf[i * NHID + j];
    __syncthreads();
    float acc = 0.f;
    #pragma unroll 8
    for (int k = 0; k < 128; k++)
        acc = fmaf(gs[k], w1[k * NHID + j], acc);   // coalesced across j
    o1[i * NHID + j] = acc + b1[j];
}

__global__ __launch_bounds__(128) void k_head2(const float* __restrict__ o1,
                                               const float* __restrict__ gamma,
                                               const float* __restrict__ beta,
                                               const float* __restrict__ w2,
                                               const float* __restrict__ b2,
                                               float* __restrict__ out){
    __shared__ float s_o1[128][129];     // 66 KB, padded
    __shared__ float sa[128], sb[128];
    int t = threadIdx.x;
    float s = 0.f, q = 0.f;
    for (int r = 0; r < 128; r++){
        float v = o1[r * NHID + t];      // coalesced
        s_o1[r][t] = v;
        s += v; q += v * v;
    }
    float mu = s * (1.f / 128.f);
    float rs = rsqrtf(q * (1.f / 128.f) - mu * mu + BN_EPS);
    float a = gamma[t] * rs;
    sa[t] = a;
    sb[t] = beta[t] - mu * a;
    __syncthreads();
    float a2 = 0.f;
    #pragma unroll 8
    for (int j = 0; j < 128; j++){
        float v = fmaf(s_o1[t][j], sa[j], sb[j]);
        a2 += fmaxf(v, 0.f) * w2[j];
    }
    out[t] = a2 + b2[0];
}

// ---------------- launch ----------------

extern "C" void kernel_launch(void* const* d_in, const int* in_sizes, int n_in,
                              void* d_out, int out_size, void* d_ws, size_t ws_size,
                              hipStream_t stream){
    const int*   x_idx    = (const int*)d_in[0];
    const int*   eidx     = (const int*)d_in[1];
    const int*   eattr    = (const int*)d_in[2];
    const int*   batch    = (const int*)d_in[3];
    const float* node_emb = (const float*)d_in[4];
    const float* edge_emb = (const float*)d_in[5];
    const float* conv_w1  = (const float*)d_in[6];
    const float* conv_w2  = (const float*)d_in[7];
    const float* bn_gamma = (const float*)d_in[8];
    const float* bn_beta  = (const float*)d_in[9];
    const float* out_w1   = (const float*)d_in[10];
    const float* out_b1   = (const float*)d_in[11];
    const float* out_bng  = (const float*)d_in[12];
    const float* out_bnb  = (const float*)d_in[13];
    const float* out_w2   = (const float*)d_in[14];
    const float* out_b2   = (const float*)d_in[15];
    float* out = (float*)d_out;

    char* base = (char*)d_ws;
    size_t off = 0;
    auto alloc = [&](size_t bytes) -> char* {
        char* r = base + off;
        off = (off + bytes + 255) & ~(size_t)255;
        return r;
    };
    float*    xbuf    = (float*)alloc((size_t)N_NODES * NHID * 4);   // 51.2 MB
    float*    h0buf   = (float*)alloc((size_t)N_NODES * NHID * 4);   // 51.2 MB (h0, then h2 in place)
    int*      row_ptr = (int*)alloc((size_t)(N_NODES + 1) * 4);
    int*      cursor  = (int*)alloc((size_t)N_NODES * 4);
    int*      counts  = (int*)alloc((size_t)N_NODES * 4);
    int*      partial = (int*)alloc(512 * 4);
    unsigned* pack    = (unsigned*)alloc((size_t)N_EDGES * 4);       // 6.4 MB
    float*    stats   = (float*)alloc(NLAYER * 256 * 4);
    float*    coef    = (float*)alloc(NLAYER * 256 * 4);
    float*    gbuf    = (float*)alloc((size_t)N_GRAPHS * NHID * 4);
    float*    o1buf   = (float*)alloc((size_t)N_GRAPHS * NHID * 4);
    (void)ws_size; (void)in_sizes; (void)n_in; (void)out_size;

    hipMemsetAsync(counts, 0, (size_t)N_NODES * 4, stream);
    hipMemsetAsync(stats, 0, NLAYER * 256 * 4, stream);

    // CSR build (edges grouped by dst), once per call, reused across 4 layers
    k_hist<<<N_EDGES / 256, 256, 0, stream>>>(eidx + N_EDGES, counts);
    k_scan_partial<<<SCAN_NB, 256, 0, stream>>>(counts, partial);
    k_scan_top<<<1, 128, 0, stream>>>(partial, SCAN_NB, row_ptr);
    k_scan_final<<<SCAN_NB, 256, 0, stream>>>(counts, partial, row_ptr);
    hipMemcpyAsync(cursor, row_ptr, (size_t)N_NODES * 4, hipMemcpyDeviceToDevice, stream);
    k_fill<<<N_EDGES / 256, 256, 0, stream>>>(eidx, eattr, cursor, pack);

    k_initx<<<(N_NODES * 32) / 256, 256, 0, stream>>>(x_idx, node_emb, (float4*)xbuf);

    for (int l = 0; l < NLAYER; l++){
        k_agg<<<(N_NODES * 64) / 256, 256, 0, stream>>>(
            xbuf, row_ptr, pack, edge_emb + (size_t)l * 20 * NHID, (float2*)h0buf);
        k_mlp<<<(N_NODES + 127) / 128, 256, 0, stream>>>(
            h0buf, conv_w1 + (size_t)l * NHID * NHID, conv_w2 + (size_t)l * NHID * NHID,
            h0buf, stats + l * 256);
        k_coef<<<1, 128, 0, stream>>>(stats + l * 256, bn_gamma + l * NHID, bn_beta + l * NHID,
                                      coef + l * 256);
        k_norm<<<(N_NODES * 32) / 256, 256, 0, stream>>>(
            (const float4*)h0buf, (float4*)xbuf, coef + l * 256);
    }

    k_pool<<<N_GRAPHS, 256, 0, stream>>>(xbuf, batch, gbuf);
    k_head1<<<N_GRAPHS, 128, 0, stream>>>(gbuf, out_w1, out_b1, o1buf);
    k_head2<<<1, 128, 0, stream>>>(o1buf, out_bng, out_bnb, out_w2, out_b2, out);
}

// Round 4
// 1579.188 us; speedup vs baseline: 1.4484x; 1.0873x over previous
//
#include <hip/hip_runtime.h>

#define N_NODES 100000
#define N_EDGES 1600000
#define N_GRAPHS 128
#define NHID 128
#define NLAYER 4
#define BN_EPS 1e-5f

#define SCAN_ITEMS 1024
#define SCAN_NB ((N_NODES + SCAN_ITEMS - 1) / SCAN_ITEMS)   // 98

__device__ __forceinline__ float4 ld4(const float* p){ return *(const float4*)p; }
__device__ __forceinline__ void st4(float* p, float4 v){ *(float4*)p = v; }

// ---------------- CSR build ----------------

__global__ void k_hist(const int* __restrict__ dst, int* __restrict__ counts){
    int e = blockIdx.x * 256 + threadIdx.x;
    if (e < N_EDGES) atomicAdd(&counts[dst[e]], 1);
}

__global__ void k_scan_partial(const int* __restrict__ counts, int* __restrict__ partial){
    __shared__ int s[256];
    int t = threadIdx.x;
    int base = blockIdx.x * SCAN_ITEMS + t * 4;
    int v = 0;
    #pragma unroll
    for (int k = 0; k < 4; k++) if (base + k < N_NODES) v += counts[base + k];
    s[t] = v;
    __syncthreads();
    for (int o = 128; o > 0; o >>= 1){
        if (t < o) s[t] += s[t + o];
        __syncthreads();
    }
    if (t == 0) partial[blockIdx.x] = s[0];
}

__global__ void k_scan_top(int* __restrict__ partial, int nb, int* __restrict__ row_ptr){
    __shared__ int s[128];
    int t = threadIdx.x;
    int v = (t < nb) ? partial[t] : 0;
    s[t] = v;
    __syncthreads();
    for (int d = 1; d < 128; d <<= 1){
        int add = (t >= d) ? s[t - d] : 0;
        __syncthreads();
        s[t] += add;
        __syncthreads();
    }
    if (t < nb) partial[t] = s[t] - v;           // exclusive
    if (t == 0) row_ptr[N_NODES] = N_EDGES;
}

__global__ void k_scan_final(const int* __restrict__ counts, const int* __restrict__ partial,
                             int* __restrict__ row_ptr){
    __shared__ int s[256];
    int t = threadIdx.x;
    int base = blockIdx.x * SCAN_ITEMS + t * 4;
    int v[4]; int tsum = 0;
    #pragma unroll
    for (int k = 0; k < 4; k++){ v[k] = (base + k < N_NODES) ? counts[base + k] : 0; tsum += v[k]; }
    s[t] = tsum;
    __syncthreads();
    for (int d = 1; d < 256; d <<= 1){
        int add = (t >= d) ? s[t - d] : 0;
        __syncthreads();
        s[t] += add;
        __syncthreads();
    }
    int off = partial[blockIdx.x] + s[t] - tsum;  // exclusive prefix for this thread
    #pragma unroll
    for (int k = 0; k < 4; k++){
        if (base + k < N_NODES) row_ptr[base + k] = off;
        off += v[k];
    }
}

__global__ void k_fill(const int* __restrict__ eidx, const int* __restrict__ eattr,
                       int* __restrict__ cursor, unsigned* __restrict__ pack){
    int e = blockIdx.x * 256 + threadIdx.x;
    if (e >= N_EDGES) return;
    int d = eidx[N_EDGES + e];
    int s = eidx[e];
    int a = eattr[e];
    int pos = atomicAdd(&cursor[d], 1);
    pack[pos] = (unsigned)s | ((unsigned)a << 17);   // src<2^17, attr<32
}

// ---------------- node embedding init ----------------

__global__ void k_initx(const int* __restrict__ x_idx, const float* __restrict__ node_emb,
                        float4* __restrict__ x4){
    int i = blockIdx.x * 256 + threadIdx.x;          // over N*32 float4s
    if (i >= N_NODES * 32) return;
    int n = i >> 5, c = i & 31;
    int id = x_idx[n];
    x4[i] = ((const float4*)node_emb)[id * 32 + c];
}

// ---------------- aggregation: h0[n] = x[n] + sum relu(x[src]+emb[attr]) ----------------
// emb table is 10 KB -> L1-resident; read directly (no LDS staging, no block startup sync)

__global__ __launch_bounds__(256) void k_agg(const float* __restrict__ x,
                      const int* __restrict__ row_ptr,
                      const unsigned* __restrict__ pack, const float* __restrict__ emb_l,
                      float2* __restrict__ h0){
    int gid = blockIdx.x * 256 + threadIdx.x;        // grid exactly N_NODES*64/256
    int node = gid >> 6;
    int lane = threadIdx.x & 63;                     // 2 channels per lane
    const float2* x2 = (const float2*)x;
    const float2* e2 = (const float2*)emb_l;
    float2 acc = x2[node * 64 + lane];
    int beg = row_ptr[node], end = row_ptr[node + 1];
    int i = beg;
    for (; i + 1 < end; i += 2){
        unsigned p0 = pack[i], p1 = pack[i + 1];
        float2 xv0 = x2[(p0 & 0x1FFFFu) * 64 + lane];
        float2 xv1 = x2[(p1 & 0x1FFFFu) * 64 + lane];
        float2 ev0 = e2[(p0 >> 17) * 64 + lane];
        float2 ev1 = e2[(p1 >> 17) * 64 + lane];
        acc.x += fmaxf(xv0.x + ev0.x, 0.f) + fmaxf(xv1.x + ev1.x, 0.f);
        acc.y += fmaxf(xv0.y + ev0.y, 0.f) + fmaxf(xv1.y + ev1.y, 0.f);
    }
    if (i < end){
        unsigned p = pack[i];
        float2 xv = x2[(p & 0x1FFFFu) * 64 + lane];
        float2 ev = e2[(p >> 17) * 64 + lane];
        acc.x += fmaxf(xv.x + ev.x, 0.f);
        acc.y += fmaxf(xv.y + ev.y, 0.f);
    }
    h0[node * 64 + lane] = acc;
}

// ---- GEMM building block: C_tile(128x128) = A(128xK=128) @ W(128x128), LDS = 34 KB ----
// Output optionally relu'd.  In-place over A is safe:
// each block reads only its own 128-row panel (all reads precede the final sync+store).

template<int RELU_OUT, int DO_STATS>
__global__ __launch_bounds__(256) void k_gemm(const float* __restrict__ A,
                                              const float* __restrict__ W,
                                              float* __restrict__ out,
                                              float* __restrict__ stats_l){
    __shared__ float As[128][36];    // 18 KB
    __shared__ float Bs[32][128];    // 16 KB (reused as stats scratch)
    const int tid = threadIdx.x;
    const int rt = tid & 15;
    const int ct = tid >> 4;
    const int row0 = blockIdx.x * 128;

    float acc[8][8];
    #pragma unroll
    for (int i = 0; i < 8; i++)
        #pragma unroll
        for (int j = 0; j < 8; j++) acc[i][j] = 0.f;

    for (int kc = 0; kc < 4; kc++){
        __syncthreads();
        #pragma unroll
        for (int q = 0; q < 4; q++){
            int f = tid + 256 * q;                  // 0..1023 float4s of A chunk
            int r = f >> 3, kq = f & 7;
            int gr = row0 + r;
            float4 v = make_float4(0.f, 0.f, 0.f, 0.f);
            if (gr < N_NODES) v = ld4(A + gr * NHID + kc * 32 + kq * 4);
            st4(&As[r][kq * 4], v);
        }
        #pragma unroll
        for (int q = 0; q < 4; q++){
            int f = tid + 256 * q;                  // 0..1023 float4s of W chunk
            int r = f >> 5, c4 = f & 31;
            st4(&Bs[r][c4 * 4], ld4(W + (kc * 32 + r) * NHID + c4 * 4));
        }
        __syncthreads();
        #pragma unroll
        for (int g = 0; g < 8; g++){                // groups of 4 k
            float av[8][4];
            #pragma unroll
            for (int i = 0; i < 8; i++){
                float4 t = ld4(&As[rt + 16 * i][g * 4]);
                av[i][0] = t.x; av[i][1] = t.y; av[i][2] = t.z; av[i][3] = t.w;
            }
            #pragma unroll
            for (int q = 0; q < 4; q++){
                float4 b0 = ld4(&Bs[g * 4 + q][ct * 8]);
                float4 b1 = ld4(&Bs[g * 4 + q][ct * 8 + 4]);
                float bv[8] = {b0.x, b0.y, b0.z, b0.w, b1.x, b1.y, b1.z, b1.w};
                #pragma unroll
                for (int i = 0; i < 8; i++)
                    #pragma unroll
                    for (int j = 0; j < 8; j++)
                        acc[i][j] = fmaf(av[i][q], bv[j], acc[i][j]);
            }
        }
    }

    if (RELU_OUT){
        #pragma unroll
        for (int i = 0; i < 8; i++)
            #pragma unroll
            for (int j = 0; j < 8; j++) acc[i][j] = fmaxf(acc[i][j], 0.f);
    }
    #pragma unroll
    for (int i = 0; i < 8; i++){
        int gr = row0 + rt + 16 * i;
        if (gr < N_NODES){
            st4(out + gr * NHID + ct * 8,
                make_float4(acc[i][0], acc[i][1], acc[i][2], acc[i][3]));
            st4(out + gr * NHID + ct * 8 + 4,
                make_float4(acc[i][4], acc[i][5], acc[i][6], acc[i][7]));
        }
    }

    if (DO_STATS){
        // padded rows contribute exactly 0 to both sums (acc stays 0) -> no masking
        __syncthreads();                 // all Bs reads complete
        float* red = &Bs[0][0];          // 2048 floats: [16][128] sums
        float* red2 = &As[0][0];         // [16][128] sumsq
        #pragma unroll
        for (int j = 0; j < 8; j++){
            float s = 0.f, q = 0.f;
            #pragma unroll
            for (int i = 0; i < 8; i++){ float v = acc[i][j]; s += v; q += v * v; }
            red[rt * 128 + ct * 8 + j] = s;
            red2[rt * 128 + ct * 8 + j] = q;
        }
        __syncthreads();
        if (tid < 128){
            float s = 0.f, q = 0.f;
            #pragma unroll
            for (int r2 = 0; r2 < 16; r2++){
                s += red[r2 * 128 + tid];
                q += red2[r2 * 128 + tid];
            }
            atomicAdd(&stats_l[tid], s);
            atomicAdd(&stats_l[128 + tid], q);
        }
    }
}

__global__ void k_coef(const float* __restrict__ stats_l, const float* __restrict__ gamma,
                       const float* __restrict__ beta, float* __restrict__ coef_l){
    int c = threadIdx.x;                            // 128
    float mu  = stats_l[c] * (1.f / N_NODES);
    float var = stats_l[128 + c] * (1.f / N_NODES) - mu * mu;
    float a = gamma[c] * rsqrtf(var + BN_EPS);
    coef_l[c] = a;
    coef_l[128 + c] = beta[c] - mu * a;
}

// ---------------- normalize + relu + residual (x updated in place) ----------------

__global__ void k_norm(const float4* __restrict__ h2, float4* __restrict__ x,
                       const float* __restrict__ coef_l){
    int i = blockIdx.x * 256 + threadIdx.x;
    if (i >= N_NODES * 32) return;
    int g = (i & 31) * 4;
    float4 h = h2[i];
    float4 xv = x[i];
    float4 r;
    r.x = fmaxf(fmaf(h.x, coef_l[g+0], coef_l[128+g+0]), 0.f) + xv.x;
    r.y = fmaxf(fmaf(h.y, coef_l[g+1], coef_l[128+g+1]), 0.f) + xv.y;
    r.z = fmaxf(fmaf(h.z, coef_l[g+2], coef_l[128+g+2]), 0.f) + xv.z;
    r.w = fmaxf(fmaf(h.w, coef_l[g+3], coef_l[128+g+3]), 0.f) + xv.w;
    x[i] = r;
}

// ---------------- pooling: one block per graph (batch is sorted) ----------------

__global__ void k_pool(const float* __restrict__ x, const int* __restrict__ batch,
                       float* __restrict__ gbuf){
    int g = blockIdx.x;
    int lo = 0, hi = N_NODES;
    while (lo < hi){ int mid = (lo + hi) >> 1; if (batch[mid] < g) lo = mid + 1; else hi = mid; }
    int start = lo;
    hi = N_NODES;
    while (lo < hi){ int mid = (lo + hi) >> 1; if (batch[mid] < g + 1) lo = mid + 1; else hi = mid; }
    int end = lo;
    int c = threadIdx.x & 127;
    int half = threadIdx.x >> 7;
    float acc = 0.f;
    for (int n = start + half; n < end; n += 2) acc += x[n * NHID + c];
    __shared__ float s[256];
    s[threadIdx.x] = acc;
    __syncthreads();
    if (threadIdx.x < 128) gbuf[g * NHID + threadIdx.x] = s[threadIdx.x] + s[threadIdx.x + 128];
}

// ---------------- output head ----------------

__global__ __launch_bounds__(128) void k_head1(const float* __restrict__ gbuf,
                                               const float* __restrict__ w1,
                                               const float* __restrict__ b1,
                                               float* __restrict__ o1){
    __shared__ float gs[128];
    int i = blockIdx.x;                  // graph row
    int j = threadIdx.x;                 // output column
    gs[j] = gbuf[i * NHID + j];
    __syncthreads();
    float acc = 0.f;
    #pragma unroll 8
    for (int k = 0; k < 128; k++)
        acc = fmaf(gs[k], w1[k * NHID + j], acc);   // coalesced across j
    o1[i * NHID + j] = acc + b1[j];
}

__global__ __launch_bounds__(128) void k_head2(const float* __restrict__ o1,
                                               const float* __restrict__ gamma,
                                               const float* __restrict__ beta,
                                               const float* __restrict__ w2,
                                               const float* __restrict__ b2,
                                               float* __restrict__ out){
    __shared__ float s_o1[128][129];     // padded
    __shared__ float sa[128], sb[128];
    int t = threadIdx.x;
    float s = 0.f, q = 0.f;
    for (int r = 0; r < 128; r++){
        float v = o1[r * NHID + t];      // coalesced
        s_o1[r][t] = v;
        s += v; q += v * v;
    }
    float mu = s * (1.f / 128.f);
    float rs = rsqrtf(q * (1.f / 128.f) - mu * mu + BN_EPS);
    float a = gamma[t] * rs;
    sa[t] = a;
    sb[t] = beta[t] - mu * a;
    __syncthreads();
    float a2 = 0.f;
    #pragma unroll 8
    for (int j = 0; j < 128; j++){
        float v = fmaf(s_o1[t][j], sa[j], sb[j]);
        a2 += fmaxf(v, 0.f) * w2[j];
    }
    out[t] = a2 + b2[0];
}

// ---------------- launch ----------------

extern "C" void kernel_launch(void* const* d_in, const int* in_sizes, int n_in,
                              void* d_out, int out_size, void* d_ws, size_t ws_size,
                              hipStream_t stream){
    const int*   x_idx    = (const int*)d_in[0];
    const int*   eidx     = (const int*)d_in[1];
    const int*   eattr    = (const int*)d_in[2];
    const int*   batch    = (const int*)d_in[3];
    const float* node_emb = (const float*)d_in[4];
    const float* edge_emb = (const float*)d_in[5];
    const float* conv_w1  = (const float*)d_in[6];
    const float* conv_w2  = (const float*)d_in[7];
    const float* bn_gamma = (const float*)d_in[8];
    const float* bn_beta  = (const float*)d_in[9];
    const float* out_w1   = (const float*)d_in[10];
    const float* out_b1   = (const float*)d_in[11];
    const float* out_bng  = (const float*)d_in[12];
    const float* out_bnb  = (const float*)d_in[13];
    const float* out_w2   = (const float*)d_in[14];
    const float* out_b2   = (const float*)d_in[15];
    float* out = (float*)d_out;

    char* base = (char*)d_ws;
    size_t off = 0;
    auto alloc = [&](size_t bytes) -> char* {
        char* r = base + off;
        off = (off + bytes + 255) & ~(size_t)255;
        return r;
    };
    float*    xbuf    = (float*)alloc((size_t)N_NODES * NHID * 4);   // 51.2 MB (x, residual)
    float*    h0buf   = (float*)alloc((size_t)N_NODES * NHID * 4);   // 51.2 MB (h0 -> t -> h2 in place)
    int*      row_ptr = (int*)alloc((size_t)(N_NODES + 1) * 4);
    int*      cursor  = (int*)alloc((size_t)N_NODES * 4);
    int*      counts  = (int*)alloc((size_t)N_NODES * 4);
    int*      partial = (int*)alloc(512 * 4);
    unsigned* pack    = (unsigned*)alloc((size_t)N_EDGES * 4);       // 6.4 MB
    float*    stats   = (float*)alloc(NLAYER * 256 * 4);
    float*    coef    = (float*)alloc(NLAYER * 256 * 4);
    float*    gbuf    = (float*)alloc((size_t)N_GRAPHS * NHID * 4);
    float*    o1buf   = (float*)alloc((size_t)N_GRAPHS * NHID * 4);
    (void)ws_size; (void)in_sizes; (void)n_in; (void)out_size;

    hipMemsetAsync(counts, 0, (size_t)N_NODES * 4, stream);
    hipMemsetAsync(stats, 0, NLAYER * 256 * 4, stream);

    // CSR build (edges grouped by dst), once per call, reused across 4 layers
    k_hist<<<N_EDGES / 256, 256, 0, stream>>>(eidx + N_EDGES, counts);
    k_scan_partial<<<SCAN_NB, 256, 0, stream>>>(counts, partial);
    k_scan_top<<<1, 128, 0, stream>>>(partial, SCAN_NB, row_ptr);
    k_scan_final<<<SCAN_NB, 256, 0, stream>>>(counts, partial, row_ptr);
    hipMemcpyAsync(cursor, row_ptr, (size_t)N_NODES * 4, hipMemcpyDeviceToDevice, stream);
    k_fill<<<N_EDGES / 256, 256, 0, stream>>>(eidx, eattr, cursor, pack);

    k_initx<<<(N_NODES * 32) / 256, 256, 0, stream>>>(x_idx, node_emb, (float4*)xbuf);

    const int gemm_grid = (N_NODES + 127) / 128;     // 782
    for (int l = 0; l < NLAYER; l++){
        k_agg<<<(N_NODES * 64) / 256, 256, 0, stream>>>(
            xbuf, row_ptr, pack, edge_emb + (size_t)l * 20 * NHID, (float2*)h0buf);
        // t = relu(h0 @ w1)   (in place)
        k_gemm<1, 0><<<gemm_grid, 256, 0, stream>>>(
            h0buf, conv_w1 + (size_t)l * NHID * NHID, h0buf, nullptr);
        // h2 = t @ w2 (+ BN stats)   (in place)
        k_gemm<0, 1><<<gemm_grid, 256, 0, stream>>>(
            h0buf, conv_w2 + (size_t)l * NHID * NHID, h0buf, stats + l * 256);
        k_coef<<<1, 128, 0, stream>>>(stats + l * 256, bn_gamma + l * NHID, bn_beta + l * NHID,
                                      coef + l * 256);
        k_norm<<<(N_NODES * 32) / 256, 256, 0, stream>>>(
            (const float4*)h0buf, (float4*)xbuf, coef + l * 256);
    }

    k_pool<<<N_GRAPHS, 256, 0, stream>>>(xbuf, batch, gbuf);
    k_head1<<<N_GRAPHS, 128, 0, stream>>>(gbuf, out_w1, out_b1, o1buf);
    k_head2<<<1, 128, 0, stream>>>(o1buf, out_bng, out_bnb, out_w2, out_b2, out);
}

// Round 5
// 1495.155 us; speedup vs baseline: 1.5298x; 1.0562x over previous
//
#include <hip/hip_runtime.h>

#define N_NODES 100000
#define N_EDGES 1600000
#define N_GRAPHS 128
#define NHID 128
#define NLAYER 4
#define BN_EPS 1e-5f

#define SCAN_ITEMS 1024
#define SCAN_NB ((N_NODES + SCAN_ITEMS - 1) / SCAN_ITEMS)   // 98

__device__ __forceinline__ float4 ld4(const float* p){ return *(const float4*)p; }
__device__ __forceinline__ void st4(float* p, float4 v){ *(float4*)p = v; }

// ---------------- CSR build ----------------

__global__ void k_hist(const int* __restrict__ dst, int* __restrict__ counts){
    int e = blockIdx.x * 256 + threadIdx.x;
    if (e < N_EDGES) atomicAdd(&counts[dst[e]], 1);
}

__global__ void k_scan_partial(const int* __restrict__ counts, int* __restrict__ partial){
    __shared__ int s[256];
    int t = threadIdx.x;
    int base = blockIdx.x * SCAN_ITEMS + t * 4;
    int v = 0;
    #pragma unroll
    for (int k = 0; k < 4; k++) if (base + k < N_NODES) v += counts[base + k];
    s[t] = v;
    __syncthreads();
    for (int o = 128; o > 0; o >>= 1){
        if (t < o) s[t] += s[t + o];
        __syncthreads();
    }
    if (t == 0) partial[blockIdx.x] = s[0];
}

__global__ void k_scan_top(int* __restrict__ partial, int nb, int* __restrict__ row_ptr){
    __shared__ int s[128];
    int t = threadIdx.x;
    int v = (t < nb) ? partial[t] : 0;
    s[t] = v;
    __syncthreads();
    for (int d = 1; d < 128; d <<= 1){
        int add = (t >= d) ? s[t - d] : 0;
        __syncthreads();
        s[t] += add;
        __syncthreads();
    }
    if (t < nb) partial[t] = s[t] - v;           // exclusive
    if (t == 0) row_ptr[N_NODES] = N_EDGES;
}

__global__ void k_scan_final(const int* __restrict__ counts, const int* __restrict__ partial,
                             int* __restrict__ row_ptr){
    __shared__ int s[256];
    int t = threadIdx.x;
    int base = blockIdx.x * SCAN_ITEMS + t * 4;
    int v[4]; int tsum = 0;
    #pragma unroll
    for (int k = 0; k < 4; k++){ v[k] = (base + k < N_NODES) ? counts[base + k] : 0; tsum += v[k]; }
    s[t] = tsum;
    __syncthreads();
    for (int d = 1; d < 256; d <<= 1){
        int add = (t >= d) ? s[t - d] : 0;
        __syncthreads();
        s[t] += add;
        __syncthreads();
    }
    int off = partial[blockIdx.x] + s[t] - tsum;  // exclusive prefix for this thread
    #pragma unroll
    for (int k = 0; k < 4; k++){
        if (base + k < N_NODES) row_ptr[base + k] = off;
        off += v[k];
    }
}

// fill CSR payloads: pack (src|attr) for layers 1-3, pack0 (x_idx[src]*20+attr) for layer 0
__global__ void k_fill(const int* __restrict__ eidx, const int* __restrict__ eattr,
                       const int* __restrict__ x_idx,
                       int* __restrict__ cursor, unsigned* __restrict__ pack,
                       unsigned short* __restrict__ pack0){
    int e = blockIdx.x * 256 + threadIdx.x;
    if (e >= N_EDGES) return;
    int d = eidx[N_EDGES + e];
    int s = eidx[e];
    int a = eattr[e];
    int pos = atomicAdd(&cursor[d], 1);
    pack[pos] = (unsigned)s | ((unsigned)a << 17);   // src<2^17, attr<32
    pack0[pos] = (unsigned short)(x_idx[s] * 20 + a); // 0..1999
}

// ---------------- layer-0 message memo table: combo[i*20+a][c] = relu(ne[i][c]+ee0[a][c]) ----

__global__ void k_combo(const float* __restrict__ node_emb, const float* __restrict__ edge_emb0,
                        float* __restrict__ combo){
    int i = blockIdx.x * 256 + threadIdx.x;          // over 2000*128
    if (i >= 2000 * NHID) return;
    int row = i >> 7, c = i & 127;
    int ni = row / 20, a = row - ni * 20;
    combo[i] = fmaxf(node_emb[ni * NHID + c] + edge_emb0[a * NHID + c], 0.f);
}

// ---------------- node embedding init ----------------

__global__ void k_initx(const int* __restrict__ x_idx, const float* __restrict__ node_emb,
                        float4* __restrict__ x4){
    int i = blockIdx.x * 256 + threadIdx.x;          // over N*32 float4s
    if (i >= N_NODES * 32) return;
    int n = i >> 5, c = i & 31;
    int id = x_idx[n];
    x4[i] = ((const float4*)node_emb)[id * 32 + c];
}

// ---------------- aggregation (layers 1-3): h0[n] = x[n] + sum relu(x[src]+emb[attr]) ------

__global__ __launch_bounds__(256) void k_agg(const float* __restrict__ x,
                      const int* __restrict__ row_ptr,
                      const unsigned* __restrict__ pack, const float* __restrict__ emb_l,
                      float2* __restrict__ h0){
    int gid = blockIdx.x * 256 + threadIdx.x;        // grid exactly N_NODES*64/256
    int node = gid >> 6;
    int lane = threadIdx.x & 63;                     // 2 channels per lane
    const float2* x2 = (const float2*)x;
    const float2* e2 = (const float2*)emb_l;
    float2 acc = x2[node * 64 + lane];
    int beg = row_ptr[node], end = row_ptr[node + 1];
    int i = beg;
    for (; i + 3 < end; i += 4){
        unsigned p0 = pack[i], p1 = pack[i+1], p2 = pack[i+2], p3 = pack[i+3];
        float2 a0 = x2[(p0 & 0x1FFFFu) * 64 + lane];
        float2 a1 = x2[(p1 & 0x1FFFFu) * 64 + lane];
        float2 a2 = x2[(p2 & 0x1FFFFu) * 64 + lane];
        float2 a3 = x2[(p3 & 0x1FFFFu) * 64 + lane];
        float2 b0 = e2[(p0 >> 17) * 64 + lane];
        float2 b1 = e2[(p1 >> 17) * 64 + lane];
        float2 b2 = e2[(p2 >> 17) * 64 + lane];
        float2 b3 = e2[(p3 >> 17) * 64 + lane];
        acc.x += (fmaxf(a0.x + b0.x, 0.f) + fmaxf(a1.x + b1.x, 0.f))
               + (fmaxf(a2.x + b2.x, 0.f) + fmaxf(a3.x + b3.x, 0.f));
        acc.y += (fmaxf(a0.y + b0.y, 0.f) + fmaxf(a1.y + b1.y, 0.f))
               + (fmaxf(a2.y + b2.y, 0.f) + fmaxf(a3.y + b3.y, 0.f));
    }
    for (; i < end; i++){
        unsigned p = pack[i];
        float2 xv = x2[(p & 0x1FFFFu) * 64 + lane];
        float2 ev = e2[(p >> 17) * 64 + lane];
        acc.x += fmaxf(xv.x + ev.x, 0.f);
        acc.y += fmaxf(xv.y + ev.y, 0.f);
    }
    h0[node * 64 + lane] = acc;
}

// ---------------- aggregation (layer 0): messages from 1 MB memo table (L2-resident) -------

__global__ __launch_bounds__(256) void k_agg0(const float* __restrict__ x,
                      const int* __restrict__ row_ptr,
                      const unsigned short* __restrict__ pack0,
                      const float* __restrict__ combo,
                      float2* __restrict__ h0){
    int gid = blockIdx.x * 256 + threadIdx.x;
    int node = gid >> 6;
    int lane = threadIdx.x & 63;
    const float2* x2 = (const float2*)x;
    const float2* c2 = (const float2*)combo;
    float2 acc = x2[node * 64 + lane];
    int beg = row_ptr[node], end = row_ptr[node + 1];
    int i = beg;
    for (; i + 3 < end; i += 4){
        int ci0 = pack0[i], ci1 = pack0[i+1], ci2 = pack0[i+2], ci3 = pack0[i+3];
        float2 m0 = c2[ci0 * 64 + lane];
        float2 m1 = c2[ci1 * 64 + lane];
        float2 m2 = c2[ci2 * 64 + lane];
        float2 m3 = c2[ci3 * 64 + lane];
        acc.x += (m0.x + m1.x) + (m2.x + m3.x);
        acc.y += (m0.y + m1.y) + (m2.y + m3.y);
    }
    for (; i < end; i++){
        float2 m = c2[pack0[i] * 64 + lane];
        acc.x += m.x;
        acc.y += m.y;
    }
    h0[node * 64 + lane] = acc;
}

// ---- GEMM building block: C_tile(128x128) = A(128xK=128) @ W(128x128), LDS = 34 KB ----
// Output optionally relu'd.  In-place over A is safe:
// each block reads only its own 128-row panel (all reads precede the final sync+store).

template<int RELU_OUT, int DO_STATS>
__global__ __launch_bounds__(256) void k_gemm(const float* __restrict__ A,
                                              const float* __restrict__ W,
                                              float* __restrict__ out,
                                              float* __restrict__ stats_l){
    __shared__ float As[128][36];    // 18 KB
    __shared__ float Bs[32][128];    // 16 KB (reused as stats scratch)
    const int tid = threadIdx.x;
    const int rt = tid & 15;
    const int ct = tid >> 4;
    const int row0 = blockIdx.x * 128;

    float acc[8][8];
    #pragma unroll
    for (int i = 0; i < 8; i++)
        #pragma unroll
        for (int j = 0; j < 8; j++) acc[i][j] = 0.f;

    for (int kc = 0; kc < 4; kc++){
        __syncthreads();
        #pragma unroll
        for (int q = 0; q < 4; q++){
            int f = tid + 256 * q;                  // 0..1023 float4s of A chunk
            int r = f >> 3, kq = f & 7;
            int gr = row0 + r;
            float4 v = make_float4(0.f, 0.f, 0.f, 0.f);
            if (gr < N_NODES) v = ld4(A + gr * NHID + kc * 32 + kq * 4);
            st4(&As[r][kq * 4], v);
        }
        #pragma unroll
        for (int q = 0; q < 4; q++){
            int f = tid + 256 * q;                  // 0..1023 float4s of W chunk
            int r = f >> 5, c4 = f & 31;
            st4(&Bs[r][c4 * 4], ld4(W + (kc * 32 + r) * NHID + c4 * 4));
        }
        __syncthreads();
        #pragma unroll
        for (int g = 0; g < 8; g++){                // groups of 4 k
            float av[8][4];
            #pragma unroll
            for (int i = 0; i < 8; i++){
                float4 t = ld4(&As[rt + 16 * i][g * 4]);
                av[i][0] = t.x; av[i][1] = t.y; av[i][2] = t.z; av[i][3] = t.w;
            }
            #pragma unroll
            for (int q = 0; q < 4; q++){
                float4 b0 = ld4(&Bs[g * 4 + q][ct * 8]);
                float4 b1 = ld4(&Bs[g * 4 + q][ct * 8 + 4]);
                float bv[8] = {b0.x, b0.y, b0.z, b0.w, b1.x, b1.y, b1.z, b1.w};
                #pragma unroll
                for (int i = 0; i < 8; i++)
                    #pragma unroll
                    for (int j = 0; j < 8; j++)
                        acc[i][j] = fmaf(av[i][q], bv[j], acc[i][j]);
            }
        }
    }

    if (RELU_OUT){
        #pragma unroll
        for (int i = 0; i < 8; i++)
            #pragma unroll
            for (int j = 0; j < 8; j++) acc[i][j] = fmaxf(acc[i][j], 0.f);
    }
    #pragma unroll
    for (int i = 0; i < 8; i++){
        int gr = row0 + rt + 16 * i;
        if (gr < N_NODES){
            st4(out + gr * NHID + ct * 8,
                make_float4(acc[i][0], acc[i][1], acc[i][2], acc[i][3]));
            st4(out + gr * NHID + ct * 8 + 4,
                make_float4(acc[i][4], acc[i][5], acc[i][6], acc[i][7]));
        }
    }

    if (DO_STATS){
        // padded rows contribute exactly 0 to both sums (acc stays 0) -> no masking
        __syncthreads();                 // all Bs reads complete
        float* red = &Bs[0][0];          // [16][128] sums
        float* red2 = &As[0][0];         // [16][128] sumsq
        #pragma unroll
        for (int j = 0; j < 8; j++){
            float s = 0.f, q = 0.f;
            #pragma unroll
            for (int i = 0; i < 8; i++){ float v = acc[i][j]; s += v; q += v * v; }
            red[rt * 128 + ct * 8 + j] = s;
            red2[rt * 128 + ct * 8 + j] = q;
        }
        __syncthreads();
        if (tid < 128){
            float s = 0.f, q = 0.f;
            #pragma unroll
            for (int r2 = 0; r2 < 16; r2++){
                s += red[r2 * 128 + tid];
                q += red2[r2 * 128 + tid];
            }
            atomicAdd(&stats_l[tid], s);
            atomicAdd(&stats_l[128 + tid], q);
        }
    }
}

__global__ void k_coef(const float* __restrict__ stats_l, const float* __restrict__ gamma,
                       const float* __restrict__ beta, float* __restrict__ coef_l){
    int c = threadIdx.x;                            // 128
    float mu  = stats_l[c] * (1.f / N_NODES);
    float var = stats_l[128 + c] * (1.f / N_NODES) - mu * mu;
    float a = gamma[c] * rsqrtf(var + BN_EPS);
    coef_l[c] = a;
    coef_l[128 + c] = beta[c] - mu * a;
}

// ---------------- normalize + relu + residual (x updated in place) ----------------

__global__ void k_norm(const float4* __restrict__ h2, float4* __restrict__ x,
                       const float* __restrict__ coef_l){
    int i = blockIdx.x * 256 + threadIdx.x;
    if (i >= N_NODES * 32) return;
    int g = (i & 31) * 4;
    float4 h = h2[i];
    float4 xv = x[i];
    float4 r;
    r.x = fmaxf(fmaf(h.x, coef_l[g+0], coef_l[128+g+0]), 0.f) + xv.x;
    r.y = fmaxf(fmaf(h.y, coef_l[g+1], coef_l[128+g+1]), 0.f) + xv.y;
    r.z = fmaxf(fmaf(h.z, coef_l[g+2], coef_l[128+g+2]), 0.f) + xv.z;
    r.w = fmaxf(fmaf(h.w, coef_l[g+3], coef_l[128+g+3]), 0.f) + xv.w;
    x[i] = r;
}

// ---------------- pooling: one block per graph (batch is sorted) ----------------

__global__ void k_pool(const float* __restrict__ x, const int* __restrict__ batch,
                       float* __restrict__ gbuf){
    int g = blockIdx.x;
    int lo = 0, hi = N_NODES;
    while (lo < hi){ int mid = (lo + hi) >> 1; if (batch[mid] < g) lo = mid + 1; else hi = mid; }
    int start = lo;
    hi = N_NODES;
    while (lo < hi){ int mid = (lo + hi) >> 1; if (batch[mid] < g + 1) lo = mid + 1; else hi = mid; }
    int end = lo;
    int c = threadIdx.x & 127;
    int half = threadIdx.x >> 7;
    float acc = 0.f;
    for (int n = start + half; n < end; n += 2) acc += x[n * NHID + c];
    __shared__ float s[256];
    s[threadIdx.x] = acc;
    __syncthreads();
    if (threadIdx.x < 128) gbuf[g * NHID + threadIdx.x] = s[threadIdx.x] + s[threadIdx.x + 128];
}

// ---------------- output head ----------------

__global__ __launch_bounds__(128) void k_head1(const float* __restrict__ gbuf,
                                               const float* __restrict__ w1,
                                               const float* __restrict__ b1,
                                               float* __restrict__ o1){
    __shared__ float gs[128];
    int i = blockIdx.x;                  // graph row
    int j = threadIdx.x;                 // output column
    gs[j] = gbuf[i * NHID + j];
    __syncthreads();
    float acc = 0.f;
    #pragma unroll 8
    for (int k = 0; k < 128; k++)
        acc = fmaf(gs[k], w1[k * NHID + j], acc);   // coalesced across j
    o1[i * NHID + j] = acc + b1[j];
}

__global__ __launch_bounds__(128) void k_head2(const float* __restrict__ o1,
                                               const float* __restrict__ gamma,
                                               const float* __restrict__ beta,
                                               const float* __restrict__ w2,
                                               const float* __restrict__ b2,
                                               float* __restrict__ out){
    __shared__ float s_o1[128][129];     // padded
    __shared__ float sa[128], sb[128];
    int t = threadIdx.x;
    float s = 0.f, q = 0.f;
    for (int r = 0; r < 128; r++){
        float v = o1[r * NHID + t];      // coalesced
        s_o1[r][t] = v;
        s += v; q += v * v;
    }
    float mu = s * (1.f / 128.f);
    float rs = rsqrtf(q * (1.f / 128.f) - mu * mu + BN_EPS);
    float a = gamma[t] * rs;
    sa[t] = a;
    sb[t] = beta[t] - mu * a;
    __syncthreads();
    float a2 = 0.f;
    #pragma unroll 8
    for (int j = 0; j < 128; j++){
        float v = fmaf(s_o1[t][j], sa[j], sb[j]);
        a2 += fmaxf(v, 0.f) * w2[j];
    }
    out[t] = a2 + b2[0];
}

// ---------------- launch ----------------

extern "C" void kernel_launch(void* const* d_in, const int* in_sizes, int n_in,
                              void* d_out, int out_size, void* d_ws, size_t ws_size,
                              hipStream_t stream){
    const int*   x_idx    = (const int*)d_in[0];
    const int*   eidx     = (const int*)d_in[1];
    const int*   eattr    = (const int*)d_in[2];
    const int*   batch    = (const int*)d_in[3];
    const float* node_emb = (const float*)d_in[4];
    const float* edge_emb = (const float*)d_in[5];
    const float* conv_w1  = (const float*)d_in[6];
    const float* conv_w2  = (const float*)d_in[7];
    const float* bn_gamma = (const float*)d_in[8];
    const float* bn_beta  = (const float*)d_in[9];
    const float* out_w1   = (const float*)d_in[10];
    const float* out_b1   = (const float*)d_in[11];
    const float* out_bng  = (const float*)d_in[12];
    const float* out_bnb  = (const float*)d_in[13];
    const float* out_w2   = (const float*)d_in[14];
    const float* out_b2   = (const float*)d_in[15];
    float* out = (float*)d_out;

    char* base = (char*)d_ws;
    size_t off = 0;
    auto alloc = [&](size_t bytes) -> char* {
        char* r = base + off;
        off = (off + bytes + 255) & ~(size_t)255;
        return r;
    };
    float*          xbuf    = (float*)alloc((size_t)N_NODES * NHID * 4);   // 51.2 MB
    float*          h0buf   = (float*)alloc((size_t)N_NODES * NHID * 4);   // 51.2 MB
    int*            row_ptr = (int*)alloc((size_t)(N_NODES + 1) * 4);
    int*            cursor  = (int*)alloc((size_t)N_NODES * 4);
    int*            counts  = (int*)alloc((size_t)N_NODES * 4);
    int*            partial = (int*)alloc(512 * 4);
    unsigned*       pack    = (unsigned*)alloc((size_t)N_EDGES * 4);       // 6.4 MB
    unsigned short* pack0   = (unsigned short*)alloc((size_t)N_EDGES * 2); // 3.2 MB
    float*          combo   = (float*)alloc((size_t)2000 * NHID * 4);      // 1.0 MB
    float*          stats   = (float*)alloc(NLAYER * 256 * 4);
    float*          coef    = (float*)alloc(NLAYER * 256 * 4);
    float*          gbuf    = (float*)alloc((size_t)N_GRAPHS * NHID * 4);
    float*          o1buf   = (float*)alloc((size_t)N_GRAPHS * NHID * 4);
    (void)ws_size; (void)in_sizes; (void)n_in; (void)out_size;

    hipMemsetAsync(counts, 0, (size_t)N_NODES * 4, stream);
    hipMemsetAsync(stats, 0, NLAYER * 256 * 4, stream);

    // CSR build (edges grouped by dst), once per call, reused across 4 layers
    k_hist<<<N_EDGES / 256, 256, 0, stream>>>(eidx + N_EDGES, counts);
    k_scan_partial<<<SCAN_NB, 256, 0, stream>>>(counts, partial);
    k_scan_top<<<1, 128, 0, stream>>>(partial, SCAN_NB, row_ptr);
    k_scan_final<<<SCAN_NB, 256, 0, stream>>>(counts, partial, row_ptr);
    hipMemcpyAsync(cursor, row_ptr, (size_t)N_NODES * 4, hipMemcpyDeviceToDevice, stream);
    k_fill<<<N_EDGES / 256, 256, 0, stream>>>(eidx, eattr, x_idx, cursor, pack, pack0);

    // layer-0 message memo table (exact same arithmetic, memoized)
    k_combo<<<(2000 * NHID) / 256, 256, 0, stream>>>(node_emb, edge_emb, combo);

    k_initx<<<(N_NODES * 32) / 256, 256, 0, stream>>>(x_idx, node_emb, (float4*)xbuf);

    const int gemm_grid = (N_NODES + 127) / 128;     // 782
    for (int l = 0; l < NLAYER; l++){
        if (l == 0){
            k_agg0<<<(N_NODES * 64) / 256, 256, 0, stream>>>(
                xbuf, row_ptr, pack0, combo, (float2*)h0buf);
        } else {
            k_agg<<<(N_NODES * 64) / 256, 256, 0, stream>>>(
                xbuf, row_ptr, pack, edge_emb + (size_t)l * 20 * NHID, (float2*)h0buf);
        }
        // t = relu(h0 @ w1)   (in place)
        k_gemm<1, 0><<<gemm_grid, 256, 0, stream>>>(
            h0buf, conv_w1 + (size_t)l * NHID * NHID, h0buf, nullptr);
        // h2 = t @ w2 (+ BN stats)   (in place)
        k_gemm<0, 1><<<gemm_grid, 256, 0, stream>>>(
            h0buf, conv_w2 + (size_t)l * NHID * NHID, h0buf, stats + l * 256);
        k_coef<<<1, 128, 0, stream>>>(stats + l * 256, bn_gamma + l * NHID, bn_beta + l * NHID,
                                      coef + l * 256);
        k_norm<<<(N_NODES * 32) / 256, 256, 0, stream>>>(
            (const float4*)h0buf, (float4*)xbuf, coef + l * 256);
    }

    k_pool<<<N_GRAPHS, 256, 0, stream>>>(xbuf, batch, gbuf);
    k_head1<<<N_GRAPHS, 128, 0, stream>>>(gbuf, out_w1, out_b1, o1buf);
    k_head2<<<1, 128, 0, stream>>>(o1buf, out_bng, out_bnb, out_w2, out_b2, out);
}